// Round 3
// baseline (371.224 us; speedup 1.0000x reference)
//
#include <hip/hip_runtime.h>

#define D_IN   256
#define HID    256
#define NNODES 100000
#define NEDGE  262144

typedef short short8   __attribute__((ext_vector_type(8)));
typedef float float4v  __attribute__((ext_vector_type(4)));

__device__ __forceinline__ unsigned short f32_to_bf16_rne(float f) {
    unsigned int u = __float_as_uint(f);
    unsigned int r = u + 0x7FFFu + ((u >> 16) & 1u);
    return (unsigned short)(r >> 16);
}
__device__ __forceinline__ float bf16_to_f32(unsigned short h) {
    return __uint_as_float(((unsigned int)h) << 16);
}

// -------- W1 (fp32 [2*256][256], k-major) -> Wt (bf16 [z][n][k]) — LDS tile transpose --------
__global__ __launch_bounds__(256) void convert_w(
    const float* __restrict__ W1, unsigned short* __restrict__ Wt)
{
    __shared__ float tile[64][65];
    const int z = blockIdx.z, kb = blockIdx.x * 64, nb = blockIdx.y * 64;
    const int t = threadIdx.x;
    const int g = t >> 6, c = t & 63;          // 4 row-groups x 64 cols
#pragma unroll
    for (int r = 0; r < 16; r++) {
        int kl = g * 16 + r;
        tile[kl][c] = W1[((size_t)(z * 256 + kb + kl)) * 256 + nb + c];
    }
    __syncthreads();
#pragma unroll
    for (int r = 0; r < 16; r++) {
        int nl = g * 16 + r;
        Wt[((size_t)(z * 256 + nb + nl)) * 256 + kb + c] = f32_to_bf16_rne(tile[c][nl]);
    }
}

// -------- Phase 1: U = Xsrc@W1_top + b1 (bf16), V = Xdst@W1_bot (bf16) --------
// 128(M) x 256(N) tile, 512 threads = 8 waves (2x4), 64x64 per wave, BK=64,
// 16x16x32 bf16 MFMA. Register-prefetch pipeline: next tile's global loads are
// issued right after the first barrier so their latency overlaps the MFMA section.
#define SA 72      // padded k-stride (ushorts): 144 B = 16B-mult, 2-way bank alias (free)

__global__ __launch_bounds__(512) void gemm_xw_mfma(
    const float* __restrict__ Xsrc, const float* __restrict__ Xdst,
    const unsigned short* __restrict__ Wt, const float* __restrict__ b1,
    unsigned short* __restrict__ U, unsigned short* __restrict__ V)
{
    const int zz = blockIdx.z;
    const float* X = zz ? Xdst : Xsrc;
    const unsigned short* Wz = Wt + (size_t)zz * 256 * 256;
    unsigned short* C = zz ? V : U;

    const int m0 = blockIdx.x * 128;

    __shared__ __align__(16) unsigned short smem[27648];   // 55.3 KB
    unsigned short* As = smem;          // [128][SA]
    unsigned short* Bs = smem + 9216;   // [256][SA]

    const int t = threadIdx.x;
    const int w = t >> 6, lane = t & 63;
    const int wm = w >> 2, wn = w & 3;          // 2 x 4 wave grid
    const int quad = lane >> 4, l16 = lane & 15;

    // per-thread staging coordinates (constant across K-steps)
    int arow[4], ac4[4], brow[4], bseg[4];
    const float* agp[4];
#pragma unroll
    for (int i = 0; i < 4; i++) {
        int s = t + i * 512;
        arow[i] = s >> 4; ac4[i] = (s & 15) << 2;
        int gr = m0 + arow[i]; if (gr >= NNODES) gr = NNODES - 1;
        agp[i] = X + (size_t)gr * D_IN + ac4[i];
        brow[i] = s >> 3; bseg[i] = (s & 7) << 3;
    }

    float4v acc[4][4];
#pragma unroll
    for (int mi = 0; mi < 4; mi++)
#pragma unroll
        for (int ni = 0; ni < 4; ni++) acc[mi][ni] = (float4v){0.f, 0.f, 0.f, 0.f};

    float4 aReg[4]; int4 bReg[4];
    // prefetch K-step 0
#pragma unroll
    for (int i = 0; i < 4; i++) {
        aReg[i] = *(const float4*)(agp[i]);
        bReg[i] = *(const int4*)(Wz + (size_t)brow[i] * 256 + bseg[i]);
    }

    for (int ks = 0; ks < D_IN; ks += 64) {
        // write current regs -> LDS (A converted fp32->bf16)
#pragma unroll
        for (int i = 0; i < 4; i++) {
            ushort4 p;
            p.x = f32_to_bf16_rne(aReg[i].x); p.y = f32_to_bf16_rne(aReg[i].y);
            p.z = f32_to_bf16_rne(aReg[i].z); p.w = f32_to_bf16_rne(aReg[i].w);
            *(ushort4*)(As + arow[i] * SA + ac4[i]) = p;
            *(int4*)(Bs + brow[i] * SA + bseg[i]) = bReg[i];
        }
        __syncthreads();

        // issue next K-step's global loads (latency hides under MFMA below)
        if (ks < 192) {
#pragma unroll
            for (int i = 0; i < 4; i++) {
                aReg[i] = *(const float4*)(agp[i] + ks + 64);
                bReg[i] = *(const int4*)(Wz + (size_t)brow[i] * 256 + ks + 64 + bseg[i]);
            }
        }

#pragma unroll
        for (int kk = 0; kk < 64; kk += 32) {
            short8 af[4], bf[4];
#pragma unroll
            for (int mi = 0; mi < 4; mi++)
                af[mi] = *(const short8*)(As + (wm * 64 + mi * 16 + l16) * SA + kk + quad * 8);
#pragma unroll
            for (int ni = 0; ni < 4; ni++)
                bf[ni] = *(const short8*)(Bs + (wn * 64 + ni * 16 + l16) * SA + kk + quad * 8);
#pragma unroll
            for (int mi = 0; mi < 4; mi++)
#pragma unroll
                for (int ni = 0; ni < 4; ni++)
                    acc[mi][ni] = __builtin_amdgcn_mfma_f32_16x16x32_bf16(
                        af[mi], bf[ni], acc[mi][ni], 0, 0, 0);
        }
        __syncthreads();
    }

    // Epilogue: bias fold (z==0 adds b1), bf16 pack, LDS-staged coalesced store.
    float bias[4];
#pragma unroll
    for (int ni = 0; ni < 4; ni++)
        bias[ni] = (zz == 0) ? b1[wn * 64 + ni * 16 + l16] : 0.f;

    unsigned short* Cs = smem;          // [128][136], aliases staging
#pragma unroll
    for (int h = 0; h < 2; h++) {       // n-halves 0..127, 128..255
        if ((wn >> 1) == h) {
#pragma unroll
            for (int mi = 0; mi < 4; mi++)
#pragma unroll
                for (int ni = 0; ni < 4; ni++) {
                    int cl = (wn & 1) * 64 + ni * 16 + l16;
#pragma unroll
                    for (int r = 0; r < 4; r++) {
                        int row = wm * 64 + mi * 16 + quad * 4 + r;
                        Cs[row * 136 + cl] = f32_to_bf16_rne(acc[mi][ni][r] + bias[ni]);
                    }
                }
        }
        __syncthreads();
#pragma unroll
        for (int i = 0; i < 4; i++) {
            int s = t + i * 512;
            int row = s >> 4, seg = s & 15;
            int gr = m0 + row;
            if (gr < NNODES)
                *(int4*)(C + (size_t)gr * HID + h * 128 + seg * 8) =
                    *(const int4*)(Cs + row * 136 + seg * 8);
        }
        __syncthreads();
    }
}

// -------- Phase 2: out[e] = relu(U[s]+V[d]) . W2 + b2   (b1 folded into U) --------
// 8 edges per wave: all 16 row-gathers issued before any reduction (MLP).
__global__ __launch_bounds__(256) void edge_score_bf16(
    const unsigned short* __restrict__ U, const unsigned short* __restrict__ V,
    const float* __restrict__ W2, const float* __restrict__ b2,
    const int* __restrict__ epos, const int* __restrict__ eneg,
    float* __restrict__ out)
{
    const int w = threadIdx.x >> 6, lane = threadIdx.x & 63;
    const int ebase = blockIdx.x * 32 + w * 8;

    const float4 w2 = *(const float4*)(W2 + lane * 4);

    const int* ei = (ebase < NEDGE) ? epos : eneg;
    const int eb2 = (ebase < NEDGE) ? ebase : ebase - NEDGE;

    int sidx[8], didx[8];
#pragma unroll
    for (int j = 0; j < 8; j++) {
        sidx[j] = ei[eb2 + j];
        didx[j] = ei[NEDGE + eb2 + j];
    }
    ushort4 uu[8], vv[8];
#pragma unroll
    for (int j = 0; j < 8; j++) {
        uu[j] = *(const ushort4*)(U + (size_t)sidx[j] * HID + lane * 4);
        vv[j] = *(const ushort4*)(V + (size_t)didx[j] * HID + lane * 4);
    }
    const float bb2 = b2[0];
#pragma unroll
    for (int j = 0; j < 8; j++) {
        float p = fmaxf(bf16_to_f32(uu[j].x) + bf16_to_f32(vv[j].x), 0.f) * w2.x
                + fmaxf(bf16_to_f32(uu[j].y) + bf16_to_f32(vv[j].y), 0.f) * w2.y
                + fmaxf(bf16_to_f32(uu[j].z) + bf16_to_f32(vv[j].z), 0.f) * w2.z
                + fmaxf(bf16_to_f32(uu[j].w) + bf16_to_f32(vv[j].w), 0.f) * w2.w;
#pragma unroll
        for (int off = 32; off; off >>= 1)
            p += __shfl_down(p, off, 64);
        if (lane == 0) out[ebase + j] = p + bb2;
    }
}

// -------- Fallback (ws too small): direct per-edge MLP --------
__global__ __launch_bounds__(256) void edge_score_direct(
    const float* __restrict__ xs_, const float* __restrict__ xd_,
    const float* __restrict__ W1, const float* __restrict__ b1,
    const float* __restrict__ W2, const float* __restrict__ b2,
    const int* __restrict__ epos, const int* __restrict__ eneg,
    float* __restrict__ out)
{
    __shared__ float xrow[2 * D_IN];
    __shared__ float red[256];
    const int e = blockIdx.x;
    const int* ei = (e < NEDGE) ? epos : eneg;
    const int e2  = (e < NEDGE) ? e : e - NEDGE;
    const int s = ei[e2];
    const int d = ei[NEDGE + e2];
    const int t = threadIdx.x;

    xrow[t]        = xs_[(size_t)s * D_IN + t];
    xrow[D_IN + t] = xd_[(size_t)d * D_IN + t];
    __syncthreads();

    float acc = b1[t];
    for (int k = 0; k < 2 * D_IN; k++)
        acc += xrow[k] * W1[(size_t)k * HID + t];
    acc = fmaxf(acc, 0.f);
    red[t] = acc * W2[t];
    __syncthreads();
    for (int st = 128; st; st >>= 1) {
        if (t < st) red[t] += red[t + st];
        __syncthreads();
    }
    if (t == 0) out[e] = red[0] + b2[0];
}

extern "C" void kernel_launch(void* const* d_in, const int* in_sizes, int n_in,
                              void* d_out, int out_size, void* d_ws, size_t ws_size,
                              hipStream_t stream) {
    const float* x_src = (const float*)d_in[0];
    const float* x_dst = (const float*)d_in[1];
    const float* W1    = (const float*)d_in[2];
    const float* b1    = (const float*)d_in[3];
    const float* W2    = (const float*)d_in[4];
    const float* b2    = (const float*)d_in[5];
    const int*   epos  = (const int*)d_in[6];
    const int*   eneg  = (const int*)d_in[7];
    float* out = (float*)d_out;

    const size_t uv   = (size_t)NNODES * HID;
    const size_t need = (2 * uv + 2 * 256 * 256) * sizeof(unsigned short);
    if (ws_size >= need) {
        unsigned short* U  = (unsigned short*)d_ws;
        unsigned short* V  = U + uv;
        unsigned short* Wt = V + uv;
        convert_w<<<dim3(4, 4, 2), 256, 0, stream>>>(W1, Wt);
        dim3 g1((NNODES + 127) / 128, 1, 2);
        gemm_xw_mfma<<<g1, 512, 0, stream>>>(x_src, x_dst, Wt, b1, U, V);
        edge_score_bf16<<<(2 * NEDGE) / 32, 256, 0, stream>>>(U, V, W2, b2, epos, eneg, out);
    } else {
        edge_score_direct<<<2 * NEDGE, 256, 0, stream>>>(x_src, x_dst, W1, b1, W2, b2, epos, eneg, out);
    }
}

// Round 4
// 334.908 us; speedup vs baseline: 1.1084x; 1.1084x over previous
//
#include <hip/hip_runtime.h>

#define D_IN   256
#define HID    256
#define NNODES 100000
#define NEDGE  262144

typedef short short8            __attribute__((ext_vector_type(8)));
typedef float float4v           __attribute__((ext_vector_type(4)));
typedef unsigned short ushort8  __attribute__((ext_vector_type(8)));

__device__ __forceinline__ unsigned short f32_to_bf16_rne(float f) {
    unsigned int u = __float_as_uint(f);
    unsigned int r = u + 0x7FFFu + ((u >> 16) & 1u);
    return (unsigned short)(r >> 16);
}
__device__ __forceinline__ float bf16_to_f32(unsigned short h) {
    return __uint_as_float(((unsigned int)h) << 16);
}

// -------- W1 (fp32 [2*256][256], k-major) -> Wt (bf16 [z][n][k]) — LDS tile transpose --------
__global__ __launch_bounds__(256) void convert_w(
    const float* __restrict__ W1, unsigned short* __restrict__ Wt)
{
    __shared__ float tile[64][65];
    const int z = blockIdx.z, kb = blockIdx.x * 64, nb = blockIdx.y * 64;
    const int t = threadIdx.x;
    const int g = t >> 6, c = t & 63;
#pragma unroll
    for (int r = 0; r < 16; r++) {
        int kl = g * 16 + r;
        tile[kl][c] = W1[((size_t)(z * 256 + kb + kl)) * 256 + nb + c];
    }
    __syncthreads();
#pragma unroll
    for (int r = 0; r < 16; r++) {
        int nl = g * 16 + r;
        Wt[((size_t)(z * 256 + nb + nl)) * 256 + kb + c] = f32_to_bf16_rne(tile[c][nl]);
    }
}

// -------- Phase 1: U = Xsrc@W1_top + b1 (bf16), V = Xdst@W1_bot (bf16) --------
// Round-2 structure (112 us, no spill): 128x256 tile, 512 thr = 8 waves (2x4),
// 64x64/wave, BK=64, 16x16x32 bf16 MFMA, fp32->bf16 fused into LDS staging.
// NOTE: register-prefetch across the MFMA section spills (round-3: +86MB scratch
// writes, 112->146 us) — do not extend staging live ranges across MFMA.
#define SA 72      // padded k-stride (ushorts): 144 B = 16B-mult, 2-way bank alias (free)

__global__ __launch_bounds__(512) void gemm_xw_mfma(
    const float* __restrict__ Xsrc, const float* __restrict__ Xdst,
    const unsigned short* __restrict__ Wt, const float* __restrict__ b1,
    unsigned short* __restrict__ U, unsigned short* __restrict__ V)
{
    const int zz = blockIdx.z;
    const float* X = zz ? Xdst : Xsrc;
    const unsigned short* Wz = Wt + (size_t)zz * 256 * 256;
    unsigned short* C = zz ? V : U;

    const int m0 = blockIdx.x * 128;

    __shared__ __align__(16) unsigned short smem[27648];   // 55.3 KB
    unsigned short* As = smem;          // [128][SA]
    unsigned short* Bs = smem + 9216;   // [256][SA]

    const int t = threadIdx.x;
    const int w = t >> 6, lane = t & 63;
    const int wm = w >> 2, wn = w & 3;          // 2 x 4 wave grid
    const int quad = lane >> 4, l16 = lane & 15;

    float4v acc[4][4];
#pragma unroll
    for (int mi = 0; mi < 4; mi++)
#pragma unroll
        for (int ni = 0; ni < 4; ni++) acc[mi][ni] = (float4v){0.f, 0.f, 0.f, 0.f};

    for (int ks = 0; ks < D_IN; ks += 64) {
        // A tile: 128 rows x 64 k fp32 -> bf16.  2048 float4 chunks / 512 thr = 4 each.
#pragma unroll
        for (int i = 0; i < 4; i++) {
            int s = t + i * 512;
            int row = s >> 4, c4 = (s & 15) << 2;
            int gr = m0 + row; if (gr >= NNODES) gr = NNODES - 1;
            float4 a = *(const float4*)(X + (size_t)gr * D_IN + ks + c4);
            ushort4 p;
            p.x = f32_to_bf16_rne(a.x); p.y = f32_to_bf16_rne(a.y);
            p.z = f32_to_bf16_rne(a.z); p.w = f32_to_bf16_rne(a.w);
            *(ushort4*)(As + row * SA + c4) = p;
        }
        // B tile: 256 n x 64 k bf16 from Wt (already [n][k]).
#pragma unroll
        for (int i = 0; i < 4; i++) {
            int s = t + i * 512;
            int n = s >> 3, seg = s & 7;
            *(int4*)(Bs + n * SA + seg * 8) =
                *(const int4*)(Wz + (size_t)n * 256 + ks + seg * 8);
        }
        __syncthreads();
#pragma unroll
        for (int kk = 0; kk < 64; kk += 32) {
            short8 af[4], bf[4];
#pragma unroll
            for (int mi = 0; mi < 4; mi++)
                af[mi] = *(const short8*)(As + (wm * 64 + mi * 16 + l16) * SA + kk + quad * 8);
#pragma unroll
            for (int ni = 0; ni < 4; ni++)
                bf[ni] = *(const short8*)(Bs + (wn * 64 + ni * 16 + l16) * SA + kk + quad * 8);
#pragma unroll
            for (int mi = 0; mi < 4; mi++)
#pragma unroll
                for (int ni = 0; ni < 4; ni++)
                    acc[mi][ni] = __builtin_amdgcn_mfma_f32_16x16x32_bf16(
                        af[mi], bf[ni], acc[mi][ni], 0, 0, 0);
        }
        __syncthreads();
    }

    // Epilogue: bias fold (z==0 adds b1), bf16 pack, LDS-staged coalesced store.
    float bias[4];
#pragma unroll
    for (int ni = 0; ni < 4; ni++)
        bias[ni] = (zz == 0) ? b1[wn * 64 + ni * 16 + l16] : 0.f;

    unsigned short* Cs = smem;          // [128][136], aliases staging
#pragma unroll
    for (int h = 0; h < 2; h++) {
        if ((wn >> 1) == h) {
#pragma unroll
            for (int mi = 0; mi < 4; mi++)
#pragma unroll
                for (int ni = 0; ni < 4; ni++) {
                    int cl = (wn & 1) * 64 + ni * 16 + l16;
#pragma unroll
                    for (int r = 0; r < 4; r++) {
                        int row = wm * 64 + mi * 16 + quad * 4 + r;
                        Cs[row * 136 + cl] = f32_to_bf16_rne(acc[mi][ni][r] + bias[ni]);
                    }
                }
        }
        __syncthreads();
#pragma unroll
        for (int i = 0; i < 4; i++) {
            int s = t + i * 512;
            int row = s >> 4, seg = s & 15;
            int gr = m0 + row;
            if (gr < NNODES)
                *(int4*)(C + (size_t)gr * HID + h * 128 + seg * 8) =
                    *(const int4*)(Cs + row * 136 + seg * 8);
        }
        __syncthreads();
    }
}

// -------- Phase 2: out[e] = relu(U[s]+V[d]) . W2 + b2   (b1 folded into U) --------
// 16 edges per wave, half-wave pairing: lanes 0-31 own edge 2p, lanes 32-63 own
// edge 2p+1. Each row gather is ONE 1 KB wave-load (16 B/lane). All 16 gathers
// issued before any reduction; 5-level xor-shuffle per edge pair.
__global__ __launch_bounds__(256) void edge_score_bf16(
    const unsigned short* __restrict__ U, const unsigned short* __restrict__ V,
    const float* __restrict__ W2, const float* __restrict__ b2,
    const int* __restrict__ epos, const int* __restrict__ eneg,
    float* __restrict__ out)
{
    const int w = threadIdx.x >> 6, lane = threadIdx.x & 63;
    const int half = lane >> 5, hl = lane & 31;
    const int ebase = blockIdx.x * 64 + w * 16;     // 16 edges per wave

    const int* ei = (ebase < NEDGE) ? epos : eneg;
    const int eb2 = (ebase < NEDGE) ? ebase : ebase - NEDGE;

    int sidx[8], didx[8];
#pragma unroll
    for (int p = 0; p < 8; p++) {
        int e = eb2 + 2 * p + half;
        sidx[p] = ei[e];
        didx[p] = ei[NEDGE + e];
    }
    ushort8 uu[8], vv[8];
#pragma unroll
    for (int p = 0; p < 8; p++)
        uu[p] = *(const ushort8*)(U + (size_t)sidx[p] * HID + hl * 8);
#pragma unroll
    for (int p = 0; p < 8; p++)
        vv[p] = *(const ushort8*)(V + (size_t)didx[p] * HID + hl * 8);

    float w2r[8];
    *(float4*)&w2r[0] = *(const float4*)(W2 + hl * 8);
    *(float4*)&w2r[4] = *(const float4*)(W2 + hl * 8 + 4);
    const float bb2 = b2[0];

#pragma unroll
    for (int p = 0; p < 8; p++) {
        float s = 0.f;
#pragma unroll
        for (int q = 0; q < 8; q++)
            s += fmaxf(bf16_to_f32(uu[p][q]) + bf16_to_f32(vv[p][q]), 0.f) * w2r[q];
#pragma unroll
        for (int off = 16; off; off >>= 1)     // xor within each 32-lane half
            s += __shfl_xor(s, off, 64);
        if (hl == 0) out[ebase + 2 * p + half] = s + bb2;
    }
}

// -------- Fallback (ws too small): direct per-edge MLP --------
__global__ __launch_bounds__(256) void edge_score_direct(
    const float* __restrict__ xs_, const float* __restrict__ xd_,
    const float* __restrict__ W1, const float* __restrict__ b1,
    const float* __restrict__ W2, const float* __restrict__ b2,
    const int* __restrict__ epos, const int* __restrict__ eneg,
    float* __restrict__ out)
{
    __shared__ float xrow[2 * D_IN];
    __shared__ float red[256];
    const int e = blockIdx.x;
    const int* ei = (e < NEDGE) ? epos : eneg;
    const int e2  = (e < NEDGE) ? e : e - NEDGE;
    const int s = ei[e2];
    const int d = ei[NEDGE + e2];
    const int t = threadIdx.x;

    xrow[t]        = xs_[(size_t)s * D_IN + t];
    xrow[D_IN + t] = xd_[(size_t)d * D_IN + t];
    __syncthreads();

    float acc = b1[t];
    for (int k = 0; k < 2 * D_IN; k++)
        acc += xrow[k] * W1[(size_t)k * HID + t];
    acc = fmaxf(acc, 0.f);
    red[t] = acc * W2[t];
    __syncthreads();
    for (int st = 128; st; st >>= 1) {
        if (t < st) red[t] += red[t + st];
        __syncthreads();
    }
    if (t == 0) out[e] = red[0] + b2[0];
}

extern "C" void kernel_launch(void* const* d_in, const int* in_sizes, int n_in,
                              void* d_out, int out_size, void* d_ws, size_t ws_size,
                              hipStream_t stream) {
    const float* x_src = (const float*)d_in[0];
    const float* x_dst = (const float*)d_in[1];
    const float* W1    = (const float*)d_in[2];
    const float* b1    = (const float*)d_in[3];
    const float* W2    = (const float*)d_in[4];
    const float* b2    = (const float*)d_in[5];
    const int*   epos  = (const int*)d_in[6];
    const int*   eneg  = (const int*)d_in[7];
    float* out = (float*)d_out;

    const size_t uv   = (size_t)NNODES * HID;
    const size_t need = (2 * uv + 2 * 256 * 256) * sizeof(unsigned short);
    if (ws_size >= need) {
        unsigned short* U  = (unsigned short*)d_ws;
        unsigned short* V  = U + uv;
        unsigned short* Wt = V + uv;
        convert_w<<<dim3(4, 4, 2), 256, 0, stream>>>(W1, Wt);
        dim3 g1((NNODES + 127) / 128, 1, 2);
        gemm_xw_mfma<<<g1, 512, 0, stream>>>(x_src, x_dst, Wt, b1, U, V);
        edge_score_bf16<<<(2 * NEDGE) / 64, 256, 0, stream>>>(U, V, W2, b2, epos, eneg, out);
    } else {
        edge_score_direct<<<2 * NEDGE, 256, 0, stream>>>(x_src, x_dst, W1, b1, W2, b2, epos, eneg, out);
    }
}